// Round 1
// baseline (34.704 us; speedup 1.0000x reference)
//
#include <hip/hip_runtime.h>
#include <stdint.h>

typedef unsigned long long u64;
typedef unsigned int u32;
typedef unsigned char u8;

#define Bn 32
#define Nn 320
#define WPN 5                  // 64-bit words per 320-bit adjacency row
#define MAXD 10
#define NH 8
#define CHS 20                 // sources per block (one bitset chunk, fits u32)
#define NCH (Nn / CHS)         // 16 chunks per graph
#define TPB Nn                 // 320 threads = one node per thread (5 waves)
#define ESTR 12                // emb_s row stride in floats
#define ADJ_WORDS (Bn * Nn * WPN)   // 51200 u64, layout [b][w][j] (SoA)

// ---------------------------------------------------------------------------
// Input-format sniffing: bool arrays may arrive as 1 byte or 4 bytes/element.
// ---------------------------------------------------------------------------
__device__ __forceinline__ bool detect_byte_mode(const u32* a32) {
    int lane = threadIdx.x & 63;
    u32 or0 = 0, or1 = 0;
    #pragma unroll
    for (int k = 0; k < 16; ++k) {
        u32 v = a32[lane + k * 64];
        or0 |= v & 0x000000FFu;
        or1 |= v & 0x0000FF00u;
    }
    bool a0 = __any(or0 != 0);
    bool a1 = __any(or1 != 0);
    return a0 && a1;
}

// ---------------------------------------------------------------------------
// Kernel 1: pack adjacency into u64 bitmask rows, SoA layout [b][w][j].
// Row j masked to j<nn, columns clamped to nn (matches reference's pair mask).
// ---------------------------------------------------------------------------
__global__ __launch_bounds__(256) void build_adj(
        const u8* __restrict__ a8,
        const int* __restrict__ nn_,
        u64* __restrict__ adjW) {
    bool bytemode = detect_byte_mode((const u32*)a8);
    int t = blockIdx.x * blockDim.x + threadIdx.x;
    if (t >= ADJ_WORDS) return;
    int j = t % Nn;
    int w = (t / Nn) % WPN;
    int b = t / (Nn * WPN);
    int nn = nn_[b];
    u64 bits = 0ull;
    if (j < nn) {
        int jbase = w * 64;
        int lim = nn - jbase; if (lim > 64) lim = 64;
        if (lim > 0) {
            long base = ((long)(b * Nn + j)) * Nn + jbase;
            if (bytemode) {
                const uint4* p = (const uint4*)(a8 + base);   // 64B contiguous
                #pragma unroll
                for (int v = 0; v < 4; ++v) {
                    uint4 x = p[v];
                    u32 n0 = ((x.x & 0x01010101u) * 0x01020408u) >> 24;
                    u32 n1 = ((x.y & 0x01010101u) * 0x01020408u) >> 24;
                    u32 n2 = ((x.z & 0x01010101u) * 0x01020408u) >> 24;
                    u32 n3 = ((x.w & 0x01010101u) * 0x01020408u) >> 24;
                    u64 nib = (u64)((n0 & 0xF) | ((n1 & 0xF) << 4) |
                                    ((n2 & 0xF) << 8) | ((n3 & 0xF) << 12));
                    bits |= nib << (v * 16);
                }
            } else {
                const uint4* p = (const uint4*)(((const u32*)a8) + base);  // 256B
                #pragma unroll
                for (int v = 0; v < 16; ++v) {
                    uint4 x = p[v];
                    u64 nib = (u64)((x.x != 0u) | ((x.y != 0u) << 1) |
                                    ((x.z != 0u) << 2) | ((x.w != 0u) << 3));
                    bits |= nib << (v * 4);
                }
            }
            if (lim < 64) bits &= (1ull << lim) - 1ull;
        }
    }
    adjW[t] = bits;
}

// ---------------------------------------------------------------------------
// Kernel 2: node-centric multi-source BFS + write.
// 512 blocks (graph x 20-source chunk) x 320 threads (one node per thread).
// Per level: S_new[v] = S_old[v] | OR_{u in N(v)} S_old[u]; newly-set bits
// record dist=level into idx_s[src][v]. One __syncthreads_count per level.
// Then the coalesced gather-write epilogue (unchanged idiom).
// ---------------------------------------------------------------------------
__global__ __launch_bounds__(TPB) void bfs_write(
        const u64* __restrict__ adjW,
        const int* __restrict__ nn_,
        const float* __restrict__ emb,
        float4* __restrict__ out4) {
    int blk = blockIdx.x;
    int b = blk >> 4;            // graph
    int c = blk & 15;            // chunk
    int t = threadIdx.x;
    int v = t;                   // my node

    __shared__ __align__(16) u64 adj_s[WPN][Nn];   // 12800 B, SoA: [w][j]
    __shared__ u32 S[2][Nn];                       // 2560 B double-buffered
    __shared__ u8 idx_s[CHS][Nn];                  // 6400 B
    __shared__ __align__(16) float emb_s[(MAXD + 2) * ESTR];  // 576 B

    if (t < (MAXD + 2) * NH) emb_s[(t >> 3) * ESTR + (t & 7)] = emb[t];

    // stage adjacency slab: 800 uint4, contiguous (SoA layout matches)
    {
        const uint4* g4 = (const uint4*)(adjW + (size_t)b * (Nn * WPN));
        uint4* d4 = (uint4*)adj_s;
        #pragma unroll
        for (int it = 0; it < 3; ++it) {
            int i = it * TPB + t;
            if (i < (Nn * WPN) / 2) d4[i] = g4[i];
        }
    }
    // zero idx tile: 1600 u32 exactly
    #pragma unroll
    for (int it = 0; it < 5; ++it) ((u32*)idx_s)[it * TPB + t] = 0;

    int nn = nn_[b];
    int base = c * CHS;

    // per-node source-bitset init (each thread writes only its own slot)
    u32 init = 0;
    if (v >= base && v < base + CHS && v < nn) init = 1u << (v - base);
    S[0][v] = init;

    // full = mask of valid sources in this chunk (for saturation early-out)
    int vs = nn - base; if (vs > CHS) vs = CHS; if (vs < 0) vs = 0;
    u32 full = (vs >= CHS) ? ((1u << CHS) - 1u) : ((1u << vs) - 1u);

    __syncthreads();
    if (init) idx_s[v - base][v] = 1;   // dist 0 -> emb idx 1 (after zeroing)

    int p = 0;
    for (int level = 1; level <= Nn; ++level) {
        const u32* Sp = S[p];
        u32 mo = Sp[v];
        u32 acc = mo;
        if (mo != full) {
            #pragma unroll
            for (int w = 0; w < WPN; ++w) {
                u64 m = adj_s[w][v];
                int ubase = w * 64;
                while (m) {
                    int u = ubase + (int)__builtin_ctzll(m);
                    m &= m - 1;
                    acc |= Sp[u];
                }
            }
        }
        u32 nw = acc & ~mo;
        S[p ^ 1][v] = acc;
        if (nw) {
            u8 val = (u8)((level < MAXD ? level : MAXD) + 1);
            u32 m2 = nw;
            while (m2) {
                int s2 = (int)__builtin_ctz(m2);
                m2 &= m2 - 1;
                idx_s[s2][v] = val;     // thread v owns column v: race-free
            }
        }
        if (__syncthreads_count(nw != 0) == 0) break;  // barrier + converge
        p ^= 1;
    }

    // ---- write phase: 20 rows x 640 float4, coalesced ----
    float4* gout = out4 + (size_t)(b * Nn + base) * (Nn * NH / 4);
    #pragma unroll
    for (int i = 0; i < 40; ++i) {
        int r = i >> 1;                       // output row 0..19
        int f = ((i & 1) ? Nn : 0) + t;       // f4 index in row, 0..639
        int e = idx_s[r][f >> 1];
        const float* ep = emb_s + e * ESTR + ((f & 1) << 2);
        gout[r * (Nn * NH / 4) + f] = *(const float4*)ep;
    }
}

extern "C" void kernel_launch(void* const* d_in, const int* in_sizes, int n_in,
                              void* d_out, int out_size, void* d_ws, size_t ws_size,
                              hipStream_t stream) {
    const u8*    adj = (const u8*)d_in[0];
    const int*   nn  = (const int*)d_in[1];
    const float* emb = (const float*)d_in[2];

    u64* adjW = (u64*)d_ws;

    build_adj<<<ADJ_WORDS / 256, 256, 0, stream>>>(adj, nn, adjW);
    bfs_write<<<Bn * NCH, TPB, 0, stream>>>(adjW, nn, emb, (float4*)d_out);
}